// Round 22
// baseline (781.928 us; speedup 1.0000x reference)
//
#include <hip/hip_runtime.h>
#include <hip/hip_bf16.h>

#define F 128
#define MGCS 60
#define NWIN 800
#define RFS 512
#define NBLK 4
#define NLAY 9
#define SQF 0.70710678118f

typedef __attribute__((ext_vector_type(8))) short s16x8;
typedef __attribute__((ext_vector_type(4))) float f32x4;

#define VMCNT(n) asm volatile("s_waitcnt vmcnt(" #n ")" ::: "memory")

__device__ __forceinline__ float gated_act(float o0, float o1, float o2) {
  o0 = fminf(fmaxf(o0, -21.f), 21.f);
  o1 = fminf(fmaxf(o1, -21.f), 21.f);
  float a = __expf(2.f * o0);
  float b = __expf(-o1);
  float r = (a - 1.f) * __builtin_amdgcn_rcpf((a + 1.f) * (1.f + b));
  return (r + o2) * SQF;
}

__device__ __forceinline__ float bf2f(short s) {
  union { unsigned u; float f; } t;
  t.u = ((unsigned)(unsigned short)s) << 16;
  return t.f;
}

// ---------------- precompute kernels ----------------

__global__ void k_cond(const float* __restrict__ mgc, const float* __restrict__ cond_w,
                       const float* __restrict__ cond_b, float* __restrict__ cond) {
  int i = blockIdx.x * blockDim.x + threadIdx.x;
  if (i >= NWIN * MGCS) return;
  int n = i / MGCS, m = i % MGCS;
  int t = n / 200, u = n % 200;
  const float* wrow = cond_w + (size_t)(u * MGCS + m) * MGCS;
  const float* mr = mgc + t * MGCS;
  float s = cond_b[u * MGCS + m];
#pragma unroll
  for (int k = 0; k < MGCS; ++k) s += mr[k] * wrow[k];
  cond[i] = tanhf(s);
}

__global__ __launch_bounds__(256) void k_ci(
    const float* __restrict__ cond, const float* __restrict__ clw,
    const float* __restrict__ clb, float* __restrict__ CI) {
  int w = blockIdx.x;
  int n0 = blockIdx.y * 128;
  __shared__ float wsh[128][61];
  __shared__ float csh[128][61];
  int tid = threadIdx.x;
  for (int idx = tid; idx < 128 * MGCS; idx += 256) {
    int f = idx / MGCS, k = idx % MGCS;
    wsh[f][k] = clw[((size_t)w * 128 + f) * MGCS + k];
  }
  for (int idx = tid; idx < 128 * MGCS; idx += 256) {
    int n = idx / MGCS, k = idx % MGCS;
    csh[n][k] = (n0 + n < NWIN) ? cond[(n0 + n) * MGCS + k] : 0.f;
  }
  __syncthreads();
  int tn = tid >> 4, tf = tid & 15;
  float acc[8][8] = {};
  for (int k = 0; k < MGCS; ++k) {
    float a[8], b[8];
#pragma unroll
    for (int i = 0; i < 8; ++i) a[i] = csh[i * 16 + tn][k];
#pragma unroll
    for (int j = 0; j < 8; ++j) b[j] = wsh[j * 16 + tf][k];
#pragma unroll
    for (int i = 0; i < 8; ++i)
#pragma unroll
      for (int j = 0; j < 8; ++j) acc[i][j] += a[i] * b[j];
  }
  float bb[8];
#pragma unroll
  for (int j = 0; j < 8; ++j) bb[j] = clb[w * 128 + j * 16 + tf];
#pragma unroll
  for (int i = 0; i < 8; ++i) {
    int n = n0 + i * 16 + tn;
    if (n < NWIN) {
#pragma unroll
      for (int j = 0; j < 8; ++j)
        CI[((size_t)w * NWIN + n) * 128 + j * 16 + tf] = acc[i][j] + bb[j];
    }
  }
}

__global__ void k_wt(const float* __restrict__ convL_w, __hip_bfloat16* __restrict__ W2) {
  int i = blockIdx.x * blockDim.x + threadIdx.x;
  const int total = NBLK * 8 * 384 * 256;
  if (i >= total) return;
  int k = i & 255;
  int tf = (i >> 8) % 384;
  int wl = i / (384 * 256);
  int t = tf >> 7, f = tf & 127;
  int k2 = k >> 7, c = k & 127;
  W2[i] = __float2bfloat16(convL_w[(((size_t)(wl * 3 + t) * 128 + f) * 128 + c) * 2 + k2]);
}

__global__ void k_wt2(const float* __restrict__ pre_w, __hip_bfloat16* __restrict__ PW) {
  int i = blockIdx.x * blockDim.x + threadIdx.x;
  if (i < NBLK * 256 * 128) PW[i] = __float2bfloat16(pre_w[i]);
}

__global__ void k_outsig(const float* __restrict__ signal, float* __restrict__ out) {
  int i = blockIdx.x * blockDim.x + threadIdx.x;
  if (i < NWIN) out[i] = signal[RFS + i];
}

// ---------------- per-block kernels ----------------

// CVh[s][tf] (bf16) = b0 + prev[s]*w0 + prev[s+1]*w1
__global__ void k_pre0(const float* __restrict__ prev, const float* __restrict__ w0,
                       const float* __restrict__ b0, __hip_bfloat16* __restrict__ CVh) {
  int i = blockIdx.x * blockDim.x + threadIdx.x;
  if (i >= 1310 * 384) return;
  int tf = i % 384, s = i / 384;
  CVh[i] = __float2bfloat16(b0[tf] + prev[s] * w0[tf * 2] + prev[s + 1] * w0[tf * 2 + 1]);
}

// layer 0: out[n][j][f] = act(CVh[n+2j][f..] + CI(n)), 8 f per thread. bf16 reads.
__global__ void k_layer0(const __hip_bfloat16* __restrict__ CVh,
                         const float* __restrict__ CIb,
                         __hip_bfloat16* __restrict__ out) {
  int i = blockIdx.x * blockDim.x + threadIdx.x;
  if (i >= NWIN * 256 * 16) return;
  int fg = i & 15;
  int rest = i >> 4;
  int j = rest & 255;
  int n = rest >> 8;
  int f0 = fg * 8;
  const __hip_bfloat16* cvr = CVh + (size_t)(n + 2 * j) * 384;
  const float* ci = CIb + (size_t)n * F;
  s16x8 c0 = *(const s16x8*)(cvr + f0);
  s16x8 c1 = *(const s16x8*)(cvr + 128 + f0);
  s16x8 c2 = *(const s16x8*)(cvr + 256 + f0);
  float4 i0a = *(const float4*)(ci + f0), i0b = *(const float4*)(ci + f0 + 4);
  float4 i1a = *(const float4*)(ci + (size_t)NWIN * F + f0);
  float4 i1b = *(const float4*)(ci + (size_t)NWIN * F + f0 + 4);
  s16x8 res;
#pragma unroll
  for (int e = 0; e < 8; ++e) {
    float o0 = bf2f(c0[e]) + ((e < 4) ? (&i0a.x)[e] : (&i0b.x)[e - 4]);
    float o1 = bf2f(c1[e]) + ((e < 4) ? (&i1a.x)[e] : (&i1b.x)[e - 4]);
    float o2 = bf2f(c2[e]);
    __hip_bfloat16 h = __float2bfloat16(gated_act(o0, o1, o2));
    res[e] = *(short*)&h;
  }
  *(s16x8*)(out + ((size_t)(n * 256 + j)) * F + f0) = res;
}

// ---- fused layer slice (R9-proven, LDS src, per-ks B loads) ----
template <int MFR, int FF, bool FLAT>
__device__ __forceinline__ void fuse_layer(
    const char* src, char* dst, const char* Wb, const float* __restrict__ bb,
    const float* __restrict__ ciA, const float* __restrict__ ciB,
    int n0, int logLW, int MV, int mbase, int fbase, int lane) {
  const int col = lane & 15, kg = lane >> 4;
  f32x4 acc[MFR][FF][3];
#pragma unroll
  for (int mf = 0; mf < MFR; ++mf)
#pragma unroll
    for (int ff = 0; ff < FF; ++ff)
#pragma unroll
      for (int g = 0; g < 3; ++g) acc[mf][ff][g] = (f32x4)(0.f);
#pragma unroll
  for (int ks = 0; ks < 8; ++ks) {
    s16x8 breg[FF][3];
#pragma unroll
    for (int ff = 0; ff < FF; ++ff)
#pragma unroll
      for (int g = 0; g < 3; ++g) {
        int tf = g * 128 + fbase + ff * 16 + col;
        breg[ff][g] = *(const s16x8*)(Wb + (size_t)tf * 512 + ks * 64 + kg * 16);
      }
    s16x8 afr[MFR];
#pragma unroll
    for (int mf = 0; mf < MFR; ++mf) {
      int row = mbase + mf * 16 + col;
      row = row < MV ? row : MV - 1;
      afr[mf] = *(const s16x8*)(src + row * 512 + ((ks * 64 + kg * 16) ^ ((row & 7) << 4)));
    }
#pragma unroll
    for (int ff = 0; ff < FF; ++ff)
#pragma unroll
      for (int g = 0; g < 3; ++g)
#pragma unroll
        for (int mf = 0; mf < MFR; ++mf)
          acc[mf][ff][g] = __builtin_amdgcn_mfma_f32_16x16x32_bf16(afr[mf], breg[ff][g], acc[mf][ff][g], 0, 0, 0);
  }
#pragma unroll
  for (int mf = 0; mf < MFR; ++mf)
#pragma unroll
    for (int ff = 0; ff < FF; ++ff) {
      int f = fbase + ff * 16 + col;
      float b0 = bb[f], b1 = bb[128 + f], b2 = bb[256 + f];
#pragma unroll
      for (int r = 0; r < 4; ++r) {
        int orow = mbase + mf * 16 + kg * 4 + r;
        if (orow < MV) {
          int n = n0 + (orow >> logLW);
          float o0 = acc[mf][ff][0][r] + b0 + ciA[n * 128 + f];
          float o1 = acc[mf][ff][1][r] + b1 + ciB[n * 128 + f];
          float o2 = acc[mf][ff][2][r] + b2;
          __hip_bfloat16 h = __float2bfloat16(gated_act(o0, o1, o2));
          if (FLAT) {
            *(short*)(dst + orow * 256 + ((f * 2) ^ ((orow & 7) << 4))) = *(short*)&h;
          } else {
            int trow = ((orow >> logLW) << (logLW - 1)) | ((orow & ((1 << logLW) - 1)) >> 1);
            int kb = ((orow & 1) * 128 + f) * 2;
            *(short*)(dst + trow * 512 + (kb ^ ((trow & 7) << 4))) = *(short*)&h;
          }
        }
      }
    }
}

#define CIL(l, t) (CIb + (size_t)((l) * 2 + (t)) * NWIN * F)

// fused layers 1-2, one window per block (800 blocks), 16 waves (4/SIMD), FF=1.
// m-split across wave groups: waves 0-7 -> m-group 0, waves 8-15 -> m-group 1.
__global__ __launch_bounds__(1024, 1) void k_fuse12(
    const __hip_bfloat16* __restrict__ A0, const __hip_bfloat16* __restrict__ W2b,
    const float* __restrict__ cb, const float* __restrict__ CIb,
    __hip_bfloat16* __restrict__ outC) {
  __shared__ char Ain[128 * 512];
  __shared__ char Bp[64 * 512];
  const int n = blockIdx.x;
  const int tid = threadIdx.x;
  const int lane = tid & 63, wid = tid >> 6;     // wid in [0,16)
  const char* srcg = (const char*)A0 + (size_t)n * 65536;
  const int half = lane >> 5, lin = (lane & 31) * 16;
#pragma unroll
  for (int it = 0; it < 4; ++it) {
    int inst = wid * 4 + it;                      // 64 insts cover 128 rows
    int row = inst * 2 + half;
    __builtin_amdgcn_global_load_lds(
        (const __attribute__((address_space(1))) unsigned int*)(srcg + row * 512 + (lin ^ ((row & 7) << 4))),
        (__attribute__((address_space(3))) unsigned int*)(Ain + inst * 1024), 16, 0, 0);
  }
  VMCNT(0);
  __syncthreads();
  const int fbase = (wid & 7) * 16;
  const int mgrp = wid >> 3;                      // 0 or 1
  const char* W0 = (const char*)W2b;
  const char* W1 = (const char*)W2b + (size_t)384 * 512;
  // l1: 128 rows -> Bp; wave-group m-split (one call per wave)
  fuse_layer<4, 1, false>(Ain, Bp, W0, cb, CIL(1, 0), CIL(1, 1), n, 7, 128, mgrp * 64, fbase, lane);
  __syncthreads();
  // l2: 64 rows -> flat Ain; wave-group m-split (MFR=2 each)
  fuse_layer<2, 1, true>(Bp, Ain, W1, cb + 384, CIL(2, 0), CIL(2, 1), n, 6, 64, mgrp * 32, fbase, lane);
  __syncthreads();
  // coalesced store of l=2 output: 64 rows x 256B, 1024 x 16B
  {
    int row = tid >> 4;
    int off = (tid & 15) * 16;
    s16x8 v = *(const s16x8*)(Ain + row * 256 + (off ^ ((row & 7) << 4)));
    *(s16x8*)((char*)outC + (size_t)n * 16384 + row * 256 + off) = v;
  }
}

// fused layers 3-8 + head, 4 windows per block, 200 blocks, 8 waves (FF=1). (R20-proven)
__global__ __launch_bounds__(512) void k_tail6(
    const __hip_bfloat16* __restrict__ C2, const __hip_bfloat16* __restrict__ W2b,
    const float* __restrict__ cb, const float* __restrict__ CIb,
    const __hip_bfloat16* __restrict__ PWb, const float* __restrict__ pb_,
    const float* __restrict__ mw_, const float* __restrict__ mb_,
    const float* __restrict__ sw_, const float* __restrict__ sb_,
    const float* __restrict__ eps_, const float* __restrict__ signal,
    float* __restrict__ prev_next, float* __restrict__ out_mean,
    float* __restrict__ out_logvar, float* __restrict__ out_tails) {
  __shared__ char Ain[128 * 512];
  __shared__ char Bp[64 * 512];
  __shared__ float psm[4][256];
  __shared__ float psv[4][256];
  const int b = blockIdx.x, n0 = b * 4;
  const int tid = threadIdx.x;
  const int lane = tid & 63, wid = tid >> 6;
  const int col = lane & 15, kg = lane >> 4;
  const char* srcg = (const char*)C2 + (size_t)n0 * 16384;
  const int half = lane >> 5, lin = (lane & 31) * 16;
#pragma unroll
  for (int it = 0; it < 8; ++it) {
    int inst = wid * 8 + it;
    int row = inst * 2 + half;
    __builtin_amdgcn_global_load_lds(
        (const __attribute__((address_space(1))) unsigned int*)(srcg + row * 512 + (lin ^ ((row & 7) << 4))),
        (__attribute__((address_space(3))) unsigned int*)(Ain + inst * 1024), 16, 0, 0);
  }
  VMCNT(0);
  __syncthreads();
  const int fbase = wid * 16;
#define WLp(lm) ((const char*)W2b + (size_t)(lm) * 384 * 512)
  fuse_layer<4, 1, false>(Ain, Bp, WLp(2), cb + 2 * 384, CIL(3, 0), CIL(3, 1), n0, 5, 128, 0, fbase, lane);
  fuse_layer<4, 1, false>(Ain, Bp, WLp(2), cb + 2 * 384, CIL(3, 0), CIL(3, 1), n0, 5, 128, 64, fbase, lane);
  __syncthreads();
  fuse_layer<4, 1, false>(Bp, Ain, WLp(3), cb + 3 * 384, CIL(4, 0), CIL(4, 1), n0, 4, 64, 0, fbase, lane);
  __syncthreads();
  fuse_layer<2, 1, false>(Ain, Bp, WLp(4), cb + 4 * 384, CIL(5, 0), CIL(5, 1), n0, 3, 32, 0, fbase, lane);
  __syncthreads();
  fuse_layer<1, 1, false>(Bp, Ain, WLp(5), cb + 5 * 384, CIL(6, 0), CIL(6, 1), n0, 2, 16, 0, fbase, lane);
  __syncthreads();
  fuse_layer<1, 1, false>(Ain, Bp, WLp(6), cb + 6 * 384, CIL(7, 0), CIL(7, 1), n0, 1, 8, 0, fbase, lane);
  __syncthreads();
  fuse_layer<1, 1, true>(Bp, Ain, WLp(7), cb + 7 * 384, CIL(8, 0), CIL(8, 1), n0, 0, 4, 0, fbase, lane);
  __syncthreads();

  // head: [4 rows pad 16][K=128] x PW[256][128]^T; 8 waves x 2 nf = 256 outputs
  {
    f32x4 acc2[2];
#pragma unroll
    for (int nf = 0; nf < 2; ++nf) acc2[nf] = (f32x4)(0.f);
    const char* PB = (const char*)PWb;
    int row = col < 4 ? col : 3;
#pragma unroll
    for (int ks = 0; ks < 4; ++ks) {
      s16x8 afr = *(const s16x8*)(Ain + row * 256 + ((ks * 64 + kg * 16) ^ ((row & 7) << 4)));
#pragma unroll
      for (int nf = 0; nf < 2; ++nf) {
        int o = wid * 32 + nf * 16 + col;
        s16x8 bfr = *(const s16x8*)(PB + (size_t)o * 256 + ks * 64 + kg * 16);
        acc2[nf] = __builtin_amdgcn_mfma_f32_16x16x32_bf16(afr, bfr, acc2[nf], 0, 0, 0);
      }
    }
#pragma unroll
    for (int nf = 0; nf < 2; ++nf) {
      int o = wid * 32 + nf * 16 + col;
      float pb = pb_[o], mw = mw_[o], sw = sw_[o];
#pragma unroll
      for (int r = 0; r < 4; ++r) {
        int m = kg * 4 + r;
        if (m < 4) {
          float p = fmaxf(acc2[nf][r] + pb, 0.f);
          psm[m][o] = p * mw;
          psv[m][o] = p * sw;
        }
      }
    }
  }
  __syncthreads();
  if (wid < 4) {
    float sm = 0.f, sv = 0.f;
#pragma unroll
    for (int e = 0; e < 4; ++e) {
      sm += psm[wid][lane * 4 + e];
      sv += psv[wid][lane * 4 + e];
    }
#pragma unroll
    for (int off = 32; off > 0; off >>= 1) {
      sm += __shfl_down(sm, off);
      sv += __shfl_down(sv, off);
    }
    if (lane == 0) {
      int nn = n0 + wid;
      float mean = sm + mb_[0];
      float logv = sv + sb_[0];
      float nx = eps_[nn] * expf(0.5f * logv) + mean;
      if (prev_next) prev_next[RFS + nn] = nx;
      if (out_mean) { out_mean[nn] = mean; out_logvar[nn] = logv; }
      if (nn >= NWIN - RFS) out_tails[nn - (NWIN - RFS)] = nx;
    }
  }
  if (prev_next && tid < 4 && n0 + tid < RFS)
    prev_next[n0 + tid] = signal[n0 + tid];
}

// ---------------- host ----------------

extern "C" void kernel_launch(void* const* d_in, const int* in_sizes, int n_in,
                              void* d_out, int out_size, void* d_ws, size_t ws_size,
                              hipStream_t stream) {
  const float* mgc      = (const float*)d_in[0];
  const float* signal   = (const float*)d_in[1];
  const float* cond_w   = (const float*)d_in[2];
  const float* cond_b   = (const float*)d_in[3];
  const float* conv0_w  = (const float*)d_in[4];
  const float* conv0_b  = (const float*)d_in[5];
  const float* convL_w  = (const float*)d_in[6];
  const float* convL_b  = (const float*)d_in[7];
  const float* condlin_w= (const float*)d_in[8];
  const float* condlin_b= (const float*)d_in[9];
  const float* pre_w    = (const float*)d_in[10];
  const float* pre_b    = (const float*)d_in[11];
  const float* mean_w   = (const float*)d_in[12];
  const float* mean_b   = (const float*)d_in[13];
  const float* std_w    = (const float*)d_in[14];
  const float* std_b    = (const float*)d_in[15];
  const float* eps      = (const float*)d_in[16];
  float* out = (float*)d_out;

  float* wsf   = (float*)d_ws;
  float* cond  = wsf;                               // 48,000 f
  float* CI    = cond + 48000;                      // 7,372,800 f
  float* prevb = CI + 7372800;                      // 5,248 f
  __hip_bfloat16* W2  = (__hip_bfloat16*)(prevb + 5248);  // 3,145,728 bf16
  __hip_bfloat16* PW  = W2 + 3145728;               // 131,072 bf16
  __hip_bfloat16* CVh = PW + 131072;                // 503,040 bf16
  __hip_bfloat16* bufA = CVh + 503040 + 64;         // l0 out: 26,214,400 bf16
  __hip_bfloat16* bufC = bufA + 26214400 + 65536;   // l2 out: 6,553,600 bf16

  k_cond<<<(NWIN * MGCS + 255) / 256, 256, 0, stream>>>(mgc, cond_w, cond_b, cond);
  k_ci<<<dim3(72, 7), 256, 0, stream>>>(cond, condlin_w, condlin_b, CI);
  k_wt<<<(NBLK * 8 * 384 * 256 + 255) / 256, 256, 0, stream>>>(convL_w, W2);
  k_wt2<<<(NBLK * 256 * 128 + 255) / 256, 256, 0, stream>>>(pre_w, PW);
  k_outsig<<<(NWIN + 255) / 256, 256, 0, stream>>>(signal, out);

  for (int blk = 0; blk < NBLK; ++blk) {
    const float* prev = (blk == 0) ? signal : (prevb + (size_t)(blk - 1) * 1312);
    const float* CIb = CI + (size_t)(blk * NLAY) * 2 * NWIN * F;
    k_pre0<<<(1310 * 384 + 255) / 256, 256, 0, stream>>>(
        prev, conv0_w + (size_t)blk * 3 * F * 2, conv0_b + (size_t)blk * 3 * F, CVh);
    k_layer0<<<(NWIN * 256 * 16 + 255) / 256, 256, 0, stream>>>(CVh, CIb, bufA);

    k_fuse12<<<NWIN, 1024, 0, stream>>>(
        bufA, W2 + (size_t)blk * 8 * 384 * 256, convL_b + (size_t)blk * 8 * 384, CIb, bufC);

    k_tail6<<<NWIN / 4, 512, 0, stream>>>(
        bufC, W2 + (size_t)blk * 8 * 384 * 256,
        convL_b + (size_t)blk * 8 * 384, CIb,
        PW + (size_t)blk * 256 * 128, pre_b + (size_t)blk * 256,
        mean_w + (size_t)blk * 256, mean_b + blk,
        std_w + (size_t)blk * 256, std_b + blk,
        eps + (size_t)blk * NWIN, signal,
        (blk < 3) ? (prevb + (size_t)blk * 1312) : nullptr,
        (blk == 3) ? (out + 800) : nullptr,
        (blk == 3) ? (out + 1600) : nullptr,
        out + 2400 + (size_t)blk * 512);
  }
}

// Round 23
// 614.430 us; speedup vs baseline: 1.2726x; 1.2726x over previous
//
#include <hip/hip_runtime.h>
#include <hip/hip_bf16.h>

#define F 128
#define MGCS 60
#define NWIN 800
#define RFS 512
#define NBLK 4
#define NLAY 9
#define SQF 0.70710678118f

typedef __attribute__((ext_vector_type(8))) short s16x8;
typedef __attribute__((ext_vector_type(4))) float f32x4;

#define VMCNT(n) asm volatile("s_waitcnt vmcnt(" #n ")" ::: "memory")

__device__ __forceinline__ float gated_act(float o0, float o1, float o2) {
  o0 = fminf(fmaxf(o0, -21.f), 21.f);
  o1 = fminf(fmaxf(o1, -21.f), 21.f);
  float a = __expf(2.f * o0);
  float b = __expf(-o1);
  float r = (a - 1.f) * __builtin_amdgcn_rcpf((a + 1.f) * (1.f + b));
  return (r + o2) * SQF;
}

__device__ __forceinline__ float bf2f(short s) {
  union { unsigned u; float f; } t;
  t.u = ((unsigned)(unsigned short)s) << 16;
  return t.f;
}

// ---------------- precompute kernels ----------------

__global__ void k_cond(const float* __restrict__ mgc, const float* __restrict__ cond_w,
                       const float* __restrict__ cond_b, float* __restrict__ cond) {
  int i = blockIdx.x * blockDim.x + threadIdx.x;
  if (i >= NWIN * MGCS) return;
  int n = i / MGCS, m = i % MGCS;
  int t = n / 200, u = n % 200;
  const float* wrow = cond_w + (size_t)(u * MGCS + m) * MGCS;
  const float* mr = mgc + t * MGCS;
  float s = cond_b[u * MGCS + m];
#pragma unroll
  for (int k = 0; k < MGCS; ++k) s += mr[k] * wrow[k];
  cond[i] = tanhf(s);
}

__global__ __launch_bounds__(256) void k_ci(
    const float* __restrict__ cond, const float* __restrict__ clw,
    const float* __restrict__ clb, float* __restrict__ CI) {
  int w = blockIdx.x;
  int n0 = blockIdx.y * 128;
  __shared__ float wsh[128][61];
  __shared__ float csh[128][61];
  int tid = threadIdx.x;
  for (int idx = tid; idx < 128 * MGCS; idx += 256) {
    int f = idx / MGCS, k = idx % MGCS;
    wsh[f][k] = clw[((size_t)w * 128 + f) * MGCS + k];
  }
  for (int idx = tid; idx < 128 * MGCS; idx += 256) {
    int n = idx / MGCS, k = idx % MGCS;
    csh[n][k] = (n0 + n < NWIN) ? cond[(n0 + n) * MGCS + k] : 0.f;
  }
  __syncthreads();
  int tn = tid >> 4, tf = tid & 15;
  float acc[8][8] = {};
  for (int k = 0; k < MGCS; ++k) {
    float a[8], b[8];
#pragma unroll
    for (int i = 0; i < 8; ++i) a[i] = csh[i * 16 + tn][k];
#pragma unroll
    for (int j = 0; j < 8; ++j) b[j] = wsh[j * 16 + tf][k];
#pragma unroll
    for (int i = 0; i < 8; ++i)
#pragma unroll
      for (int j = 0; j < 8; ++j) acc[i][j] += a[i] * b[j];
  }
  float bb[8];
#pragma unroll
  for (int j = 0; j < 8; ++j) bb[j] = clb[w * 128 + j * 16 + tf];
#pragma unroll
  for (int i = 0; i < 8; ++i) {
    int n = n0 + i * 16 + tn;
    if (n < NWIN) {
#pragma unroll
      for (int j = 0; j < 8; ++j)
        CI[((size_t)w * NWIN + n) * 128 + j * 16 + tf] = acc[i][j] + bb[j];
    }
  }
}

__global__ void k_wt(const float* __restrict__ convL_w, __hip_bfloat16* __restrict__ W2) {
  int i = blockIdx.x * blockDim.x + threadIdx.x;
  const int total = NBLK * 8 * 384 * 256;
  if (i >= total) return;
  int k = i & 255;
  int tf = (i >> 8) % 384;
  int wl = i / (384 * 256);
  int t = tf >> 7, f = tf & 127;
  int k2 = k >> 7, c = k & 127;
  W2[i] = __float2bfloat16(convL_w[(((size_t)(wl * 3 + t) * 128 + f) * 128 + c) * 2 + k2]);
}

__global__ void k_wt2(const float* __restrict__ pre_w, __hip_bfloat16* __restrict__ PW) {
  int i = blockIdx.x * blockDim.x + threadIdx.x;
  if (i < NBLK * 256 * 128) PW[i] = __float2bfloat16(pre_w[i]);
}

__global__ void k_outsig(const float* __restrict__ signal, float* __restrict__ out) {
  int i = blockIdx.x * blockDim.x + threadIdx.x;
  if (i < NWIN) out[i] = signal[RFS + i];
}

// ---------------- per-block kernels ----------------

// CVh[s][tf] (bf16) = b0 + prev[s]*w0 + prev[s+1]*w1
__global__ void k_pre0(const float* __restrict__ prev, const float* __restrict__ w0,
                       const float* __restrict__ b0, __hip_bfloat16* __restrict__ CVh) {
  int i = blockIdx.x * blockDim.x + threadIdx.x;
  if (i >= 1310 * 384) return;
  int tf = i % 384, s = i / 384;
  CVh[i] = __float2bfloat16(b0[tf] + prev[s] * w0[tf * 2] + prev[s + 1] * w0[tf * 2 + 1]);
}

// layer 0: out[n][j][f] = act(CVh[n+2j][f..] + CI(n)), 8 f per thread. bf16 reads.
__global__ void k_layer0(const __hip_bfloat16* __restrict__ CVh,
                         const float* __restrict__ CIb,
                         __hip_bfloat16* __restrict__ out) {
  int i = blockIdx.x * blockDim.x + threadIdx.x;
  if (i >= NWIN * 256 * 16) return;
  int fg = i & 15;
  int rest = i >> 4;
  int j = rest & 255;
  int n = rest >> 8;
  int f0 = fg * 8;
  const __hip_bfloat16* cvr = CVh + (size_t)(n + 2 * j) * 384;
  const float* ci = CIb + (size_t)n * F;
  s16x8 c0 = *(const s16x8*)(cvr + f0);
  s16x8 c1 = *(const s16x8*)(cvr + 128 + f0);
  s16x8 c2 = *(const s16x8*)(cvr + 256 + f0);
  float4 i0a = *(const float4*)(ci + f0), i0b = *(const float4*)(ci + f0 + 4);
  float4 i1a = *(const float4*)(ci + (size_t)NWIN * F + f0);
  float4 i1b = *(const float4*)(ci + (size_t)NWIN * F + f0 + 4);
  s16x8 res;
#pragma unroll
  for (int e = 0; e < 8; ++e) {
    float o0 = bf2f(c0[e]) + ((e < 4) ? (&i0a.x)[e] : (&i0b.x)[e - 4]);
    float o1 = bf2f(c1[e]) + ((e < 4) ? (&i1a.x)[e] : (&i1b.x)[e - 4]);
    float o2 = bf2f(c2[e]);
    __hip_bfloat16 h = __float2bfloat16(gated_act(o0, o1, o2));
    res[e] = *(short*)&h;
  }
  *(s16x8*)(out + ((size_t)(n * 256 + j)) * F + f0) = res;
}

// ---- fused layer slice (R9-proven, LDS src, per-ks B loads) ----
template <int MFR, int FF, bool FLAT>
__device__ __forceinline__ void fuse_layer(
    const char* src, char* dst, const char* Wb, const float* __restrict__ bb,
    const float* __restrict__ ciA, const float* __restrict__ ciB,
    int n0, int logLW, int MV, int mbase, int fbase, int lane) {
  const int col = lane & 15, kg = lane >> 4;
  f32x4 acc[MFR][FF][3];
#pragma unroll
  for (int mf = 0; mf < MFR; ++mf)
#pragma unroll
    for (int ff = 0; ff < FF; ++ff)
#pragma unroll
      for (int g = 0; g < 3; ++g) acc[mf][ff][g] = (f32x4)(0.f);
#pragma unroll
  for (int ks = 0; ks < 8; ++ks) {
    s16x8 breg[FF][3];
#pragma unroll
    for (int ff = 0; ff < FF; ++ff)
#pragma unroll
      for (int g = 0; g < 3; ++g) {
        int tf = g * 128 + fbase + ff * 16 + col;
        breg[ff][g] = *(const s16x8*)(Wb + (size_t)tf * 512 + ks * 64 + kg * 16);
      }
    s16x8 afr[MFR];
#pragma unroll
    for (int mf = 0; mf < MFR; ++mf) {
      int row = mbase + mf * 16 + col;
      row = row < MV ? row : MV - 1;
      afr[mf] = *(const s16x8*)(src + row * 512 + ((ks * 64 + kg * 16) ^ ((row & 7) << 4)));
    }
#pragma unroll
    for (int ff = 0; ff < FF; ++ff)
#pragma unroll
      for (int g = 0; g < 3; ++g)
#pragma unroll
        for (int mf = 0; mf < MFR; ++mf)
          acc[mf][ff][g] = __builtin_amdgcn_mfma_f32_16x16x32_bf16(afr[mf], breg[ff][g], acc[mf][ff][g], 0, 0, 0);
  }
#pragma unroll
  for (int mf = 0; mf < MFR; ++mf)
#pragma unroll
    for (int ff = 0; ff < FF; ++ff) {
      int f = fbase + ff * 16 + col;
      float b0 = bb[f], b1 = bb[128 + f], b2 = bb[256 + f];
#pragma unroll
      for (int r = 0; r < 4; ++r) {
        int orow = mbase + mf * 16 + kg * 4 + r;
        if (orow < MV) {
          int n = n0 + (orow >> logLW);
          float o0 = acc[mf][ff][0][r] + b0 + ciA[n * 128 + f];
          float o1 = acc[mf][ff][1][r] + b1 + ciB[n * 128 + f];
          float o2 = acc[mf][ff][2][r] + b2;
          __hip_bfloat16 h = __float2bfloat16(gated_act(o0, o1, o2));
          if (FLAT) {
            *(short*)(dst + orow * 256 + ((f * 2) ^ ((orow & 7) << 4))) = *(short*)&h;
          } else {
            int trow = ((orow >> logLW) << (logLW - 1)) | ((orow & ((1 << logLW) - 1)) >> 1);
            int kb = ((orow & 1) * 128 + f) * 2;
            *(short*)(dst + trow * 512 + (kb ^ ((trow & 7) << 4))) = *(short*)&h;
          }
        }
      }
    }
}

#define CIL(l, t) (CIb + (size_t)((l) * 2 + (t)) * NWIN * F)

// fused layers 1-2, one window per block (800 blocks), 8 waves. (R15-proven, 81us)
__global__ __launch_bounds__(512, 1) void k_fuse12(
    const __hip_bfloat16* __restrict__ A0, const __hip_bfloat16* __restrict__ W2b,
    const float* __restrict__ cb, const float* __restrict__ CIb,
    __hip_bfloat16* __restrict__ outC) {
  __shared__ char Ain[128 * 512];
  __shared__ char Bp[64 * 512];
  const int n = blockIdx.x;
  const int tid = threadIdx.x;
  const int lane = tid & 63, wid = tid >> 6;
  const char* srcg = (const char*)A0 + (size_t)n * 65536;
  const int half = lane >> 5, lin = (lane & 31) * 16;
#pragma unroll
  for (int it = 0; it < 8; ++it) {
    int inst = wid * 8 + it;
    int row = inst * 2 + half;
    __builtin_amdgcn_global_load_lds(
        (const __attribute__((address_space(1))) unsigned int*)(srcg + row * 512 + (lin ^ ((row & 7) << 4))),
        (__attribute__((address_space(3))) unsigned int*)(Ain + inst * 1024), 16, 0, 0);
  }
  VMCNT(0);
  __syncthreads();
  const int fbase = wid * 16;
  const char* W0 = (const char*)W2b;
  const char* W1 = (const char*)W2b + (size_t)384 * 512;
  const float* c1A = CIL(1, 0);
  const float* c1B = CIL(1, 1);
  const float* c2A = CIL(2, 0);
  const float* c2B = CIL(2, 1);
  fuse_layer<4, 1, false>(Ain, Bp, W0, cb, c1A, c1B, n, 7, 128, 0, fbase, lane);
  fuse_layer<4, 1, false>(Ain, Bp, W0, cb, c1A, c1B, n, 7, 128, 64, fbase, lane);
  __syncthreads();
  fuse_layer<4, 1, true>(Bp, Ain, W1, cb + 384, c2A, c2B, n, 6, 64, 0, fbase, lane);
  __syncthreads();
  // coalesced store of l=2 output: 64 rows x 256B
#pragma unroll
  for (int p = 0; p < 2; ++p) {
    int idx = p * 512 + tid;
    int row = idx >> 4;
    int off = (idx & 15) * 16;
    s16x8 v = *(const s16x8*)(Ain + row * 256 + (off ^ ((row & 7) << 4)));
    *(s16x8*)((char*)outC + (size_t)n * 16384 + row * 256 + off) = v;
  }
}

// fused layers 3-8 + head, 4 windows per block, 200 blocks, 8 waves (FF=1). (R20-proven)
__global__ __launch_bounds__(512) void k_tail6(
    const __hip_bfloat16* __restrict__ C2, const __hip_bfloat16* __restrict__ W2b,
    const float* __restrict__ cb, const float* __restrict__ CIb,
    const __hip_bfloat16* __restrict__ PWb, const float* __restrict__ pb_,
    const float* __restrict__ mw_, const float* __restrict__ mb_,
    const float* __restrict__ sw_, const float* __restrict__ sb_,
    const float* __restrict__ eps_, const float* __restrict__ signal,
    float* __restrict__ prev_next, float* __restrict__ out_mean,
    float* __restrict__ out_logvar, float* __restrict__ out_tails) {
  __shared__ char Ain[128 * 512];
  __shared__ char Bp[64 * 512];
  __shared__ float psm[4][256];
  __shared__ float psv[4][256];
  const int b = blockIdx.x, n0 = b * 4;
  const int tid = threadIdx.x;
  const int lane = tid & 63, wid = tid >> 6;
  const int col = lane & 15, kg = lane >> 4;
  const char* srcg = (const char*)C2 + (size_t)n0 * 16384;
  const int half = lane >> 5, lin = (lane & 31) * 16;
#pragma unroll
  for (int it = 0; it < 8; ++it) {
    int inst = wid * 8 + it;
    int row = inst * 2 + half;
    __builtin_amdgcn_global_load_lds(
        (const __attribute__((address_space(1))) unsigned int*)(srcg + row * 512 + (lin ^ ((row & 7) << 4))),
        (__attribute__((address_space(3))) unsigned int*)(Ain + inst * 1024), 16, 0, 0);
  }
  VMCNT(0);
  __syncthreads();
  const int fbase = wid * 16;
#define WLp(lm) ((const char*)W2b + (size_t)(lm) * 384 * 512)
  fuse_layer<4, 1, false>(Ain, Bp, WLp(2), cb + 2 * 384, CIL(3, 0), CIL(3, 1), n0, 5, 128, 0, fbase, lane);
  fuse_layer<4, 1, false>(Ain, Bp, WLp(2), cb + 2 * 384, CIL(3, 0), CIL(3, 1), n0, 5, 128, 64, fbase, lane);
  __syncthreads();
  fuse_layer<4, 1, false>(Bp, Ain, WLp(3), cb + 3 * 384, CIL(4, 0), CIL(4, 1), n0, 4, 64, 0, fbase, lane);
  __syncthreads();
  fuse_layer<2, 1, false>(Ain, Bp, WLp(4), cb + 4 * 384, CIL(5, 0), CIL(5, 1), n0, 3, 32, 0, fbase, lane);
  __syncthreads();
  fuse_layer<1, 1, false>(Bp, Ain, WLp(5), cb + 5 * 384, CIL(6, 0), CIL(6, 1), n0, 2, 16, 0, fbase, lane);
  __syncthreads();
  fuse_layer<1, 1, false>(Ain, Bp, WLp(6), cb + 6 * 384, CIL(7, 0), CIL(7, 1), n0, 1, 8, 0, fbase, lane);
  __syncthreads();
  fuse_layer<1, 1, true>(Bp, Ain, WLp(7), cb + 7 * 384, CIL(8, 0), CIL(8, 1), n0, 0, 4, 0, fbase, lane);
  __syncthreads();

  // head: [4 rows pad 16][K=128] x PW[256][128]^T; 8 waves x 2 nf = 256 outputs
  {
    f32x4 acc2[2];
#pragma unroll
    for (int nf = 0; nf < 2; ++nf) acc2[nf] = (f32x4)(0.f);
    const char* PB = (const char*)PWb;
    int row = col < 4 ? col : 3;
#pragma unroll
    for (int ks = 0; ks < 4; ++ks) {
      s16x8 afr = *(const s16x8*)(Ain + row * 256 + ((ks * 64 + kg * 16) ^ ((row & 7) << 4)));
#pragma unroll
      for (int nf = 0; nf < 2; ++nf) {
        int o = wid * 32 + nf * 16 + col;
        s16x8 bfr = *(const s16x8*)(PB + (size_t)o * 256 + ks * 64 + kg * 16);
        acc2[nf] = __builtin_amdgcn_mfma_f32_16x16x32_bf16(afr, bfr, acc2[nf], 0, 0, 0);
      }
    }
#pragma unroll
    for (int nf = 0; nf < 2; ++nf) {
      int o = wid * 32 + nf * 16 + col;
      float pb = pb_[o], mw = mw_[o], sw = sw_[o];
#pragma unroll
      for (int r = 0; r < 4; ++r) {
        int m = kg * 4 + r;
        if (m < 4) {
          float p = fmaxf(acc2[nf][r] + pb, 0.f);
          psm[m][o] = p * mw;
          psv[m][o] = p * sw;
        }
      }
    }
  }
  __syncthreads();
  if (wid < 4) {
    float sm = 0.f, sv = 0.f;
#pragma unroll
    for (int e = 0; e < 4; ++e) {
      sm += psm[wid][lane * 4 + e];
      sv += psv[wid][lane * 4 + e];
    }
#pragma unroll
    for (int off = 32; off > 0; off >>= 1) {
      sm += __shfl_down(sm, off);
      sv += __shfl_down(sv, off);
    }
    if (lane == 0) {
      int nn = n0 + wid;
      float mean = sm + mb_[0];
      float logv = sv + sb_[0];
      float nx = eps_[nn] * expf(0.5f * logv) + mean;
      if (prev_next) prev_next[RFS + nn] = nx;
      if (out_mean) { out_mean[nn] = mean; out_logvar[nn] = logv; }
      if (nn >= NWIN - RFS) out_tails[nn - (NWIN - RFS)] = nx;
    }
  }
  if (prev_next && tid < 4 && n0 + tid < RFS)
    prev_next[n0 + tid] = signal[n0 + tid];
}

// ---------------- host ----------------

extern "C" void kernel_launch(void* const* d_in, const int* in_sizes, int n_in,
                              void* d_out, int out_size, void* d_ws, size_t ws_size,
                              hipStream_t stream) {
  const float* mgc      = (const float*)d_in[0];
  const float* signal   = (const float*)d_in[1];
  const float* cond_w   = (const float*)d_in[2];
  const float* cond_b   = (const float*)d_in[3];
  const float* conv0_w  = (const float*)d_in[4];
  const float* conv0_b  = (const float*)d_in[5];
  const float* convL_w  = (const float*)d_in[6];
  const float* convL_b  = (const float*)d_in[7];
  const float* condlin_w= (const float*)d_in[8];
  const float* condlin_b= (const float*)d_in[9];
  const float* pre_w    = (const float*)d_in[10];
  const float* pre_b    = (const float*)d_in[11];
  const float* mean_w   = (const float*)d_in[12];
  const float* mean_b   = (const float*)d_in[13];
  const float* std_w    = (const float*)d_in[14];
  const float* std_b    = (const float*)d_in[15];
  const float* eps      = (const float*)d_in[16];
  float* out = (float*)d_out;

  float* wsf   = (float*)d_ws;
  float* cond  = wsf;                               // 48,000 f
  float* CI    = cond + 48000;                      // 7,372,800 f
  float* prevb = CI + 7372800;                      // 5,248 f
  __hip_bfloat16* W2  = (__hip_bfloat16*)(prevb + 5248);  // 3,145,728 bf16
  __hip_bfloat16* PW  = W2 + 3145728;               // 131,072 bf16
  __hip_bfloat16* CVh = PW + 131072;                // 503,040 bf16
  __hip_bfloat16* bufA = CVh + 503040 + 64;         // l0 out: 26,214,400 bf16
  __hip_bfloat16* bufC = bufA + 26214400 + 65536;   // l2 out: 6,553,600 bf16

  k_cond<<<(NWIN * MGCS + 255) / 256, 256, 0, stream>>>(mgc, cond_w, cond_b, cond);
  k_ci<<<dim3(72, 7), 256, 0, stream>>>(cond, condlin_w, condlin_b, CI);
  k_wt<<<(NBLK * 8 * 384 * 256 + 255) / 256, 256, 0, stream>>>(convL_w, W2);
  k_wt2<<<(NBLK * 256 * 128 + 255) / 256, 256, 0, stream>>>(pre_w, PW);
  k_outsig<<<(NWIN + 255) / 256, 256, 0, stream>>>(signal, out);

  for (int blk = 0; blk < NBLK; ++blk) {
    const float* prev = (blk == 0) ? signal : (prevb + (size_t)(blk - 1) * 1312);
    const float* CIb = CI + (size_t)(blk * NLAY) * 2 * NWIN * F;
    k_pre0<<<(1310 * 384 + 255) / 256, 256, 0, stream>>>(
        prev, conv0_w + (size_t)blk * 3 * F * 2, conv0_b + (size_t)blk * 3 * F, CVh);
    k_layer0<<<(NWIN * 256 * 16 + 255) / 256, 256, 0, stream>>>(CVh, CIb, bufA);

    k_fuse12<<<NWIN, 512, 0, stream>>>(
        bufA, W2 + (size_t)blk * 8 * 384 * 256, convL_b + (size_t)blk * 8 * 384, CIb, bufC);

    k_tail6<<<NWIN / 4, 512, 0, stream>>>(
        bufC, W2 + (size_t)blk * 8 * 384 * 256,
        convL_b + (size_t)blk * 8 * 384, CIb,
        PW + (size_t)blk * 256 * 128, pre_b + (size_t)blk * 256,
        mean_w + (size_t)blk * 256, mean_b + blk,
        std_w + (size_t)blk * 256, std_b + blk,
        eps + (size_t)blk * NWIN, signal,
        (blk < 3) ? (prevb + (size_t)blk * 1312) : nullptr,
        (blk == 3) ? (out + 800) : nullptr,
        (blk == 3) ? (out + 1600) : nullptr,
        out + 2400 + (size_t)blk * 512);
  }
}